// Round 7
// baseline (112.411 us; speedup 1.0000x reference)
//
#include <hip/hip_runtime.h>

constexpr int NNODES_C = 50000;
constexpr int D = 16;
constexpr int NT = 16;
constexpr int NXCD = 8;
constexpr size_t PK_STRIDE = (size_t)NNODES_C * NT;   // u32 elements per pk copy

// Replicated layout (needs ws_size >= 28,800,064 B):
//   pk8  : u32[8][50000*16] @ 0            (25,600,000 B)  per-XCD histograms
//   tcnt : int[16]          @ 25,600,000   (64 B)
//   tlist: int[16*50000]    @ 25,600,064   (3,200,000 B)
constexpr size_t ROFF_TCNT  = 25600000;
constexpr size_t ROFF_TLIST = 25600064;
constexpr size_t R_NEED     = ROFF_TLIST + 3200000;
constexpr size_t R_ZERO     = ROFF_TLIST;   // pk8 + tcnt

// Fallback single-copy layout (R6 behavior):
constexpr size_t OFF_TCNT  = 3200000;
constexpr size_t OFF_TLIST = 3200064;
constexpr size_t F_ZERO    = OFF_TLIST;

// pk packing: low16 = #out-edges to type t, high16 = #in-edges from type t.

__global__ __launch_bounds__(256)
void edge_kernel_rep(const int* __restrict__ ei,
                     const int* __restrict__ types,
                     unsigned int* __restrict__ pk8,
                     int E) {
    unsigned int xcd;
    asm volatile("s_getreg_b32 %0, hwreg(HW_REG_XCC_ID)" : "=s"(xcd));
    unsigned int* __restrict__ mypk = pk8 + (size_t)(xcd & (NXCD - 1)) * PK_STRIDE;

    const int i = (blockIdx.x * blockDim.x + threadIdx.x) * 4;
    if (i >= E) return;
    if (i + 3 < E) {
        const int4 s4 = *reinterpret_cast<const int4*>(ei + i);
        const int4 t4 = *reinterpret_cast<const int4*>(ei + E + i);
        const int ss[4] = {s4.x, s4.y, s4.z, s4.w};
        const int tt[4] = {t4.x, t4.y, t4.z, t4.w};
        #pragma unroll
        for (int k = 0; k < 4; ++k) {
            const int ts = types[ss[k]];
            const int td = types[tt[k]];
            // workgroup-scope relaxed: executes in XCD-local L2, no write-through.
            __hip_atomic_fetch_add(&mypk[ss[k] * NT + td], 1u,
                                   __ATOMIC_RELAXED, __HIP_MEMORY_SCOPE_WORKGROUP);
            __hip_atomic_fetch_add(&mypk[tt[k] * NT + ts], 0x10000u,
                                   __ATOMIC_RELAXED, __HIP_MEMORY_SCOPE_WORKGROUP);
        }
    } else {
        for (int e = i; e < E; ++e) {
            const int s = ei[e];
            const int t = ei[E + e];
            __hip_atomic_fetch_add(&mypk[s * NT + types[t]], 1u,
                                   __ATOMIC_RELAXED, __HIP_MEMORY_SCOPE_WORKGROUP);
            __hip_atomic_fetch_add(&mypk[t * NT + types[s]], 0x10000u,
                                   __ATOMIC_RELAXED, __HIP_MEMORY_SCOPE_WORKGROUP);
        }
    }
}

__global__ __launch_bounds__(256)
void edge_kernel(const int* __restrict__ ei,
                 const int* __restrict__ types,
                 unsigned int* __restrict__ pk,
                 int E) {
    const int i = (blockIdx.x * blockDim.x + threadIdx.x) * 4;
    if (i >= E) return;
    if (i + 3 < E) {
        const int4 s4 = *reinterpret_cast<const int4*>(ei + i);
        const int4 t4 = *reinterpret_cast<const int4*>(ei + E + i);
        const int ss[4] = {s4.x, s4.y, s4.z, s4.w};
        const int tt[4] = {t4.x, t4.y, t4.z, t4.w};
        #pragma unroll
        for (int k = 0; k < 4; ++k) {
            const int ts = types[ss[k]];
            const int td = types[tt[k]];
            atomicAdd(&pk[ss[k] * NT + td], 1u);
            atomicAdd(&pk[tt[k] * NT + ts], 0x10000u);
        }
    } else {
        for (int e = i; e < E; ++e) {
            const int s = ei[e];
            const int t = ei[E + e];
            atomicAdd(&pk[s * NT + types[t]], 1u);
            atomicAdd(&pk[t * NT + types[s]], 0x10000u);
        }
    }
}

__global__ __launch_bounds__(256)
void list_kernel(const int* __restrict__ types,
                 int* __restrict__ tcnt,
                 int* __restrict__ tlist,
                 int N) {
    __shared__ int lcnt[NT];
    __shared__ int lbase[NT];
    if (threadIdx.x < NT) lcnt[threadIdx.x] = 0;
    __syncthreads();

    const int n = blockIdx.x * 256 + threadIdx.x;
    int ty = 0, lr = 0;
    const bool valid = (n < N);
    if (valid) {
        ty = types[n];
        lr = atomicAdd(&lcnt[ty], 1);        // LDS atomic: cheap
    }
    __syncthreads();

    if (threadIdx.x < NT)
        lbase[threadIdx.x] = atomicAdd(&tcnt[threadIdx.x], lcnt[threadIdx.x]);
    __syncthreads();

    if (valid)
        tlist[ty * NNODES_C + lbase[ty] + lr] = n;
}

// Node kernel (R6 structure) + ncopies-merge of replicated pk.
//  - block <-> type ty; R[ty] (16KB) loaded ONCE into registers.
//  - nodes streamed in 64-node batches through LDS.
//  - packed u32 copies summed directly (both halves increment-only, no overflow).
__global__ __launch_bounds__(256)
void node_kernel(const float* __restrict__ reps,
                 const float* __restrict__ rmaps,
                 const unsigned int* __restrict__ pk,
                 const int* __restrict__ tcnt,
                 const int* __restrict__ tlist,
                 float* __restrict__ out,
                 int N, int ncopies) {
    const int ty  = blockIdx.y;                  // block-uniform type
    const int cnt = tcnt[ty];
    if ((int)(blockIdx.x * 64) >= cnt) return;   // whole-block uniform exit

    const int tid = threadIdx.x;
    const int w   = tid >> 6;                    // wave id 0..3
    const int l   = tid & 63;                    // lane
    const int tg  = l >> 4;                      // type group 0..3
    const int r   = l & 15;                      // output row 0..15

    // R fragment: R[ty][tg*4+jt][r][0..15], jt=0..3 -> 16 float4 in VGPRs
    float4 Rf[4][4];
    {
        const float* Rbase = rmaps + (((size_t)ty * NT + tg * 4) * D + r) * D;
        #pragma unroll
        for (int jt = 0; jt < 4; ++jt)
            #pragma unroll
            for (int q = 0; q < 4; ++q)
                Rf[jt][q] = *reinterpret_cast<const float4*>(Rbase + jt * D * D + q * 4);
    }

    __shared__ int   NI[64];
    __shared__ float X[64][16];     // node x vectors
    __shared__ float C[64][16];     // per-type net counts (float)
    __shared__ int   PD[64][4];     // partial in-degree sums
    __shared__ float IDG[64];       // 1/deg (0 if deg==0)

    float part = 0.0f;

    for (int base = blockIdx.x * 64; base < cnt; base += gridDim.x * 64) {
        const int nb = min(64, cnt - base);

        __syncthreads();            // protect LDS from previous consume
        if (tid < nb) NI[tid] = tlist[ty * NNODES_C + base + tid];
        __syncthreads();

        const int b = tid >> 2, q = tid & 3;
        if (b < nb) {
            const int n = NI[b];
            const uint4* prow = reinterpret_cast<const uint4*>(pk + (size_t)n * NT) + q;
            uint4 pw = prow[0];
            for (int c = 1; c < ncopies; ++c) {
                const uint4 p2 = prow[(size_t)c * (PK_STRIDE / 4)];
                pw.x += p2.x; pw.y += p2.y; pw.z += p2.z; pw.w += p2.w;
            }
            const unsigned int ws4[4] = {pw.x, pw.y, pw.z, pw.w};
            int hsum = 0;
            #pragma unroll
            for (int j = 0; j < 4; ++j) {
                const int hi = (int)(ws4[j] >> 16);
                const int lo = (int)(ws4[j] & 0xFFFFu);
                C[b][q * 4 + j] = (float)(lo - hi);
                hsum += hi;
            }
            PD[b][q] = hsum;
            #pragma unroll
            for (int j = 0; j < 4; ++j)
                X[b][q * 4 + j] = reps[(q * 4 + j) * N + n];
        }
        __syncthreads();
        if (tid < nb) {
            const int dg = PD[tid][0] + PD[tid][1] + PD[tid][2] + PD[tid][3];
            IDG[tid] = (dg > 0) ? (1.0f / (float)dg) : 0.0f;
        }
        __syncthreads();

        // consume: wave w owns nodes w, w+4, ...
        for (int bb = w; bb < nb; bb += 4) {
            const float4 x0 = *reinterpret_cast<const float4*>(&X[bb][0]);
            const float4 x1 = *reinterpret_cast<const float4*>(&X[bb][4]);
            const float4 x2 = *reinterpret_cast<const float4*>(&X[bb][8]);
            const float4 x3 = *reinterpret_cast<const float4*>(&X[bb][12]);
            const float4 c4 = *reinterpret_cast<const float4*>(&C[bb][tg * 4]);
            const float idg = IDG[bb];
            const float ca[4] = {c4.x, c4.y, c4.z, c4.w};

            float y = 0.0f;
            #pragma unroll
            for (int jt = 0; jt < 4; ++jt) {
                float s = 0.0f;
                s = fmaf(Rf[jt][0].x, x0.x, s); s = fmaf(Rf[jt][0].y, x0.y, s);
                s = fmaf(Rf[jt][0].z, x0.z, s); s = fmaf(Rf[jt][0].w, x0.w, s);
                s = fmaf(Rf[jt][1].x, x1.x, s); s = fmaf(Rf[jt][1].y, x1.y, s);
                s = fmaf(Rf[jt][1].z, x1.z, s); s = fmaf(Rf[jt][1].w, x1.w, s);
                s = fmaf(Rf[jt][2].x, x2.x, s); s = fmaf(Rf[jt][2].y, x2.y, s);
                s = fmaf(Rf[jt][2].z, x2.z, s); s = fmaf(Rf[jt][2].w, x2.w, s);
                s = fmaf(Rf[jt][3].x, x3.x, s); s = fmaf(Rf[jt][3].y, x3.y, s);
                s = fmaf(Rf[jt][3].z, x3.z, s); s = fmaf(Rf[jt][3].w, x3.w, s);
                y = fmaf(ca[jt], s, y);
            }
            // reduce over tg (lane bits 4,5): butterfly
            y += __shfl_xor(y, 16);
            y += __shfl_xor(y, 32);
            if (l < 16) part = fmaf(y * y, idg, part);
        }
    }

    // block reduction -> single atomic
    #pragma unroll
    for (int off = 32; off > 0; off >>= 1)
        part += __shfl_down(part, off);
    __shared__ float wpart[4];
    const int lane = threadIdx.x & 63;
    const int wid  = threadIdx.x >> 6;
    if (lane == 0) wpart[wid] = part;
    __syncthreads();
    if (threadIdx.x == 0) {
        const float v = wpart[0] + wpart[1] + wpart[2] + wpart[3];
        if (v != 0.0f) atomicAdd(out, v);
    }
}

extern "C" void kernel_launch(void* const* d_in, const int* in_sizes, int n_in,
                              void* d_out, int out_size, void* d_ws, size_t ws_size,
                              hipStream_t stream) {
    const float* reps  = (const float*)d_in[0];   // [16, N]
    const float* rmaps = (const float*)d_in[1];   // [16,16,16,16]
    const int*   ei    = (const int*)d_in[2];     // [2, E]
    const int*   types = (const int*)d_in[3];     // [N]
    float* out = (float*)d_out;

    const int E = in_sizes[2] / 2;
    const int N = in_sizes[3];

    char* ws = (char*)d_ws;
    const bool rep = (ws_size >= R_NEED);

    unsigned int* pk = (unsigned int*)ws;
    int* tcnt  = (int*)(ws + (rep ? ROFF_TCNT  : OFF_TCNT));
    int* tlist = (int*)(ws + (rep ? ROFF_TLIST : OFF_TLIST));

    hipMemsetAsync(d_ws, 0, rep ? R_ZERO : F_ZERO, stream);
    hipMemsetAsync(d_out, 0, sizeof(float), stream);

    if (rep)
        edge_kernel_rep<<<(E / 4 + 255) / 256, 256, 0, stream>>>(ei, types, pk, E);
    else
        edge_kernel<<<(E / 4 + 255) / 256, 256, 0, stream>>>(ei, types, pk, E);

    list_kernel<<<(N + 255) / 256, 256, 0, stream>>>(types, tcnt, tlist, N);

    dim3 grid(52, NT);
    node_kernel<<<grid, 256, 0, stream>>>(reps, rmaps, pk, tcnt, tlist, out, N,
                                          rep ? NXCD : 1);
}

// Round 8
// 90.999 us; speedup vs baseline: 1.2353x; 1.2353x over previous
//
#include <hip/hip_runtime.h>

constexpr int NNODES_C = 50000;
constexpr int D = 16;
constexpr int NT = 16;
constexpr int E_C = 800000;

// Bucketed-histogram pipeline constants
constexpr int NODE_P = 512;              // nodes per partition
constexpr int P      = 98;               // ceil(50000/512)
constexpr int CHUNK  = 5120;             // edges per block in count/scatter
constexpr int NBLK   = 157;              // ceil(800000/5120)

// Fast-path ws layout (bytes):
//   entries: u32[2E]        @ 0           (6,400,000)
//   pk     : u32[N*16]      @ 6,400,000   (3,200,000)  lo16=out, hi16=in
//   cnt_g  : u32[NBLK*P]    @ 9,600,000   (61,544)
//   base_g : u32[NBLK*P]    @ 9,661,568   (61,544)
//   tcnt   : int[16]        @ 9,723,136   (64)
//   tlist  : int[16*N]      @ 9,723,200   (3,200,000)
constexpr size_t OFF_ENT   = 0;
constexpr size_t OFF_PK    = 6400000;
constexpr size_t OFF_CNT   = 9600000;
constexpr size_t OFF_BASE  = 9661568;
constexpr size_t OFF_TCNT  = 9723136;
constexpr size_t OFF_TLIST = 9723200;
constexpr size_t WS_NEED   = OFF_TLIST + 3200000;

// Fallback (R6) layout: pk @0, tcnt @3.2M, tlist @3.2M+64
constexpr size_t F_TCNT  = 3200000;
constexpr size_t F_TLIST = 3200064;

// ---------- fast path: bucketed LDS histogram ----------

__global__ __launch_bounds__(256)
void count_kernel(const int* __restrict__ ei, unsigned int* __restrict__ cnt_g,
                  int E) {
    __shared__ unsigned int cnt[P];
    const int tid = threadIdx.x;
    for (int p = tid; p < P; p += 256) cnt[p] = 0;
    __syncthreads();
    const int start = blockIdx.x * CHUNK;
    const int end   = min(start + CHUNK, E);
    for (int e = start + tid; e < end; e += 256) {
        const int s = ei[e];
        const int d = ei[E + e];
        atomicAdd(&cnt[s >> 9], 1u);
        atomicAdd(&cnt[d >> 9], 1u);
    }
    __syncthreads();
    for (int p = tid; p < P; p += 256)
        cnt_g[blockIdx.x * P + p] = cnt[p];
}

__global__ __launch_bounds__(256)
void scan_kernel(const unsigned int* __restrict__ cnt_g,
                 unsigned int* __restrict__ base_g) {
    __shared__ unsigned int sm[NBLK * P];   // 61,544 B
    __shared__ unsigned int aux[P];
    const int tid = threadIdx.x;
    for (int i = tid; i < NBLK * P; i += 256) sm[i] = cnt_g[i];
    __syncthreads();
    if (tid < P) {
        unsigned int run = 0;
        for (int b = 0; b < NBLK; ++b) {
            const unsigned int v = sm[b * P + tid];
            sm[b * P + tid] = run;
            run += v;
        }
        aux[tid] = run;                      // bucket total
    }
    __syncthreads();
    if (tid == 0) {
        unsigned int acc = 0;
        for (int p = 0; p < P; ++p) { const unsigned int t = aux[p]; aux[p] = acc; acc += t; }
    }
    __syncthreads();
    if (tid < P) {
        const unsigned int s = aux[tid];
        for (int b = 0; b < NBLK; ++b)
            base_g[b * P + tid] = sm[b * P + tid] + s;
    }
}

__global__ __launch_bounds__(256)
void scatter_kernel(const int* __restrict__ ei, const int* __restrict__ types,
                    const unsigned int* __restrict__ base_g,
                    unsigned int* __restrict__ entries, int E) {
    __shared__ unsigned int cur[P];
    const int tid = threadIdx.x;
    for (int p = tid; p < P; p += 256) cur[p] = base_g[blockIdx.x * P + p];
    __syncthreads();
    const int start = blockIdx.x * CHUNK;
    const int end   = min(start + CHUNK, E);
    for (int e = start + tid; e < end; e += 256) {
        const int s = ei[e];
        const int d = ei[E + e];
        const unsigned int ts = (unsigned int)types[s];
        const unsigned int td = (unsigned int)types[d];
        const unsigned int ps = atomicAdd(&cur[s >> 9], 1u);
        entries[ps] = ((unsigned int)s << 5) | td;           // dir=0: out at src
        const unsigned int pd = atomicAdd(&cur[d >> 9], 1u);
        entries[pd] = ((unsigned int)d << 5) | 0x10u | ts;   // dir=1: in at dst
    }
}

__global__ __launch_bounds__(256)
void hist_kernel(const unsigned int* __restrict__ entries,
                 const unsigned int* __restrict__ base_g,
                 unsigned int* __restrict__ pk, int N, int E2) {
    __shared__ unsigned int hist[NODE_P * NT];   // 32 KB
    const int tid = threadIdx.x;
    const int p   = blockIdx.x;
    for (int i = tid; i < NODE_P * NT; i += 256) hist[i] = 0;
    __syncthreads();
    const unsigned int start = base_g[p];                       // row 0 = bucket starts
    const unsigned int end   = (p + 1 < P) ? base_g[p + 1] : (unsigned int)E2;
    for (unsigned int i = start + tid; i < end; i += 256) {
        const unsigned int e  = entries[i];
        const unsigned int nl = (e >> 5) & (NODE_P - 1);
        const unsigned int add = (e & 0x10u) ? 0x10000u : 1u;
        atomicAdd(&hist[nl * NT + (e & 0xFu)], add);
    }
    __syncthreads();
    const int nn = min(NODE_P, N - p * NODE_P);
    unsigned int* dst = pk + (size_t)p * NODE_P * NT;
    for (int i = tid; i < nn * NT; i += 256) dst[i] = hist[i];
}

// ---------- fallback edge kernel (R6, global atomics) ----------

__global__ __launch_bounds__(256)
void edge_kernel(const int* __restrict__ ei, const int* __restrict__ types,
                 unsigned int* __restrict__ pk, int E) {
    const int i = (blockIdx.x * blockDim.x + threadIdx.x) * 4;
    if (i >= E) return;
    if (i + 3 < E) {
        const int4 s4 = *reinterpret_cast<const int4*>(ei + i);
        const int4 t4 = *reinterpret_cast<const int4*>(ei + E + i);
        const int ss[4] = {s4.x, s4.y, s4.z, s4.w};
        const int tt[4] = {t4.x, t4.y, t4.z, t4.w};
        #pragma unroll
        for (int k = 0; k < 4; ++k) {
            atomicAdd(&pk[ss[k] * NT + types[tt[k]]], 1u);
            atomicAdd(&pk[tt[k] * NT + types[ss[k]]], 0x10000u);
        }
    } else {
        for (int e = i; e < E; ++e) {
            const int s = ei[e];
            const int t = ei[E + e];
            atomicAdd(&pk[s * NT + types[t]], 1u);
            atomicAdd(&pk[t * NT + types[s]], 0x10000u);
        }
    }
}

// ---------- list + node (R6 structure, single pk copy) ----------

__global__ __launch_bounds__(256)
void list_kernel(const int* __restrict__ types,
                 int* __restrict__ tcnt, int* __restrict__ tlist, int N) {
    __shared__ int lcnt[NT];
    __shared__ int lbase[NT];
    if (threadIdx.x < NT) lcnt[threadIdx.x] = 0;
    __syncthreads();

    const int n = blockIdx.x * 256 + threadIdx.x;
    int ty = 0, lr = 0;
    const bool valid = (n < N);
    if (valid) {
        ty = types[n];
        lr = atomicAdd(&lcnt[ty], 1);
    }
    __syncthreads();
    if (threadIdx.x < NT)
        lbase[threadIdx.x] = atomicAdd(&tcnt[threadIdx.x], lcnt[threadIdx.x]);
    __syncthreads();
    if (valid)
        tlist[ty * NNODES_C + lbase[ty] + lr] = n;
}

__global__ __launch_bounds__(256)
void node_kernel(const float* __restrict__ reps,
                 const float* __restrict__ rmaps,
                 const unsigned int* __restrict__ pk,
                 const int* __restrict__ tcnt,
                 const int* __restrict__ tlist,
                 float* __restrict__ out, int N) {
    const int ty  = blockIdx.y;
    const int cnt = tcnt[ty];
    if ((int)(blockIdx.x * 64) >= cnt) return;

    const int tid = threadIdx.x;
    const int w   = tid >> 6;
    const int l   = tid & 63;
    const int tg  = l >> 4;
    const int r   = l & 15;

    float4 Rf[4][4];
    {
        const float* Rbase = rmaps + (((size_t)ty * NT + tg * 4) * D + r) * D;
        #pragma unroll
        for (int jt = 0; jt < 4; ++jt)
            #pragma unroll
            for (int q = 0; q < 4; ++q)
                Rf[jt][q] = *reinterpret_cast<const float4*>(Rbase + jt * D * D + q * 4);
    }

    __shared__ int   NI[64];
    __shared__ float X[64][16];
    __shared__ float C[64][16];
    __shared__ int   PD[64][4];
    __shared__ float IDG[64];

    float part = 0.0f;

    for (int base = blockIdx.x * 64; base < cnt; base += gridDim.x * 64) {
        const int nb = min(64, cnt - base);

        __syncthreads();
        if (tid < nb) NI[tid] = tlist[ty * NNODES_C + base + tid];
        __syncthreads();

        const int b = tid >> 2, q = tid & 3;
        if (b < nb) {
            const int n = NI[b];
            const uint4 pw = reinterpret_cast<const uint4*>(pk + (size_t)n * NT)[q];
            const unsigned int ws4[4] = {pw.x, pw.y, pw.z, pw.w};
            int hsum = 0;
            #pragma unroll
            for (int j = 0; j < 4; ++j) {
                const int hi = (int)(ws4[j] >> 16);
                const int lo = (int)(ws4[j] & 0xFFFFu);
                C[b][q * 4 + j] = (float)(lo - hi);
                hsum += hi;
            }
            PD[b][q] = hsum;
            #pragma unroll
            for (int j = 0; j < 4; ++j)
                X[b][q * 4 + j] = reps[(q * 4 + j) * N + n];
        }
        __syncthreads();
        if (tid < nb) {
            const int dg = PD[tid][0] + PD[tid][1] + PD[tid][2] + PD[tid][3];
            IDG[tid] = (dg > 0) ? (1.0f / (float)dg) : 0.0f;
        }
        __syncthreads();

        for (int bb = w; bb < nb; bb += 4) {
            const float4 x0 = *reinterpret_cast<const float4*>(&X[bb][0]);
            const float4 x1 = *reinterpret_cast<const float4*>(&X[bb][4]);
            const float4 x2 = *reinterpret_cast<const float4*>(&X[bb][8]);
            const float4 x3 = *reinterpret_cast<const float4*>(&X[bb][12]);
            const float4 c4 = *reinterpret_cast<const float4*>(&C[bb][tg * 4]);
            const float idg = IDG[bb];
            const float ca[4] = {c4.x, c4.y, c4.z, c4.w};

            float y = 0.0f;
            #pragma unroll
            for (int jt = 0; jt < 4; ++jt) {
                float s = 0.0f;
                s = fmaf(Rf[jt][0].x, x0.x, s); s = fmaf(Rf[jt][0].y, x0.y, s);
                s = fmaf(Rf[jt][0].z, x0.z, s); s = fmaf(Rf[jt][0].w, x0.w, s);
                s = fmaf(Rf[jt][1].x, x1.x, s); s = fmaf(Rf[jt][1].y, x1.y, s);
                s = fmaf(Rf[jt][1].z, x1.z, s); s = fmaf(Rf[jt][1].w, x1.w, s);
                s = fmaf(Rf[jt][2].x, x2.x, s); s = fmaf(Rf[jt][2].y, x2.y, s);
                s = fmaf(Rf[jt][2].z, x2.z, s); s = fmaf(Rf[jt][2].w, x2.w, s);
                s = fmaf(Rf[jt][3].x, x3.x, s); s = fmaf(Rf[jt][3].y, x3.y, s);
                s = fmaf(Rf[jt][3].w, x3.w, s); s = fmaf(Rf[jt][3].z, x3.z, s);
                y = fmaf(ca[jt], s, y);
            }
            y += __shfl_xor(y, 16);
            y += __shfl_xor(y, 32);
            if (l < 16) part = fmaf(y * y, idg, part);
        }
    }

    #pragma unroll
    for (int off = 32; off > 0; off >>= 1)
        part += __shfl_down(part, off);
    __shared__ float wpart[4];
    const int lane = threadIdx.x & 63;
    const int wid  = threadIdx.x >> 6;
    if (lane == 0) wpart[wid] = part;
    __syncthreads();
    if (threadIdx.x == 0) {
        const float v = wpart[0] + wpart[1] + wpart[2] + wpart[3];
        if (v != 0.0f) atomicAdd(out, v);
    }
}

extern "C" void kernel_launch(void* const* d_in, const int* in_sizes, int n_in,
                              void* d_out, int out_size, void* d_ws, size_t ws_size,
                              hipStream_t stream) {
    const float* reps  = (const float*)d_in[0];   // [16, N]
    const float* rmaps = (const float*)d_in[1];   // [16,16,16,16]
    const int*   ei    = (const int*)d_in[2];     // [2, E]
    const int*   types = (const int*)d_in[3];     // [N]
    float* out = (float*)d_out;

    const int E = in_sizes[2] / 2;
    const int N = in_sizes[3];

    char* ws = (char*)d_ws;
    const bool fast = (N == NNODES_C && E == E_C && ws_size >= WS_NEED);

    hipMemsetAsync(d_out, 0, sizeof(float), stream);

    if (fast) {
        unsigned int* entries = (unsigned int*)(ws + OFF_ENT);
        unsigned int* pk      = (unsigned int*)(ws + OFF_PK);
        unsigned int* cnt_g   = (unsigned int*)(ws + OFF_CNT);
        unsigned int* base_g  = (unsigned int*)(ws + OFF_BASE);
        int* tcnt  = (int*)(ws + OFF_TCNT);
        int* tlist = (int*)(ws + OFF_TLIST);

        hipMemsetAsync(tcnt, 0, 64, stream);

        count_kernel  <<<NBLK, 256, 0, stream>>>(ei, cnt_g, E);
        scan_kernel   <<<1,    256, 0, stream>>>(cnt_g, base_g);
        scatter_kernel<<<NBLK, 256, 0, stream>>>(ei, types, base_g, entries, E);
        hist_kernel   <<<P,    256, 0, stream>>>(entries, base_g, pk, N, 2 * E);

        list_kernel<<<(N + 255) / 256, 256, 0, stream>>>(types, tcnt, tlist, N);
        dim3 grid(52, NT);
        node_kernel<<<grid, 256, 0, stream>>>(reps, rmaps, pk, tcnt, tlist, out, N);
    } else {
        unsigned int* pk = (unsigned int*)ws;
        int* tcnt  = (int*)(ws + F_TCNT);
        int* tlist = (int*)(ws + F_TLIST);

        hipMemsetAsync(d_ws, 0, F_TLIST, stream);
        edge_kernel<<<(E / 4 + 255) / 256, 256, 0, stream>>>(ei, types, pk, E);
        list_kernel<<<(N + 255) / 256, 256, 0, stream>>>(types, tcnt, tlist, N);
        dim3 grid(52, NT);
        node_kernel<<<grid, 256, 0, stream>>>(reps, rmaps, pk, tcnt, tlist, out, N);
    }
}

// Round 9
// 74.591 us; speedup vs baseline: 1.5070x; 1.2200x over previous
//
#include <hip/hip_runtime.h>

constexpr int NNODES_C = 50000;
constexpr int D = 16;
constexpr int NT = 16;
constexpr int E_C = 800000;

// Bucketed pipeline constants
constexpr int NODE_P = 512;              // nodes per partition
constexpr int P      = 98;               // ceil(50000/512)
constexpr int CAP    = 32768;            // u16 entry slots per partition (avg fill 16.3K)
constexpr int CHUNK  = 5120;             // edges per scatter block
constexpr int NBLK   = 157;              // ceil(800000/5120)

// Fast-path ws layout (bytes):
//   entries: u16[P*CAP]   @ 0          (6,422,528)
//   pk     : u32[N*16]    @ 6,422,528  (3,200,000)  lo16=out-cnt, hi16=in-cnt
//   gcur   : u32[P]       @ 9,622,528  (392, padded to 512)
//   tcnt   : int[16]      @ 9,623,040  (64)
//   tlist  : int[16*N]    @ 9,623,104  (3,200,000)
constexpr size_t OFF_ENT   = 0;
constexpr size_t OFF_PK    = 6422528;
constexpr size_t OFF_GCUR  = 9622528;
constexpr size_t OFF_TCNT  = 9623040;
constexpr size_t OFF_TLIST = 9623104;
constexpr size_t WS_NEED   = OFF_TLIST + 3200000;

// Fallback (R6) layout: pk @0, tcnt @3.2M, tlist @3.2M+64
constexpr size_t F_TCNT  = 3200000;
constexpr size_t F_TLIST = 3200064;

// ---------- fast path ----------

__global__ void init_kernel(unsigned int* __restrict__ gcur,
                            int* __restrict__ tcnt,
                            float* __restrict__ out) {
    const int t = threadIdx.x;
    if (t < P)  gcur[t] = (unsigned int)t * CAP;
    if (t < NT) tcnt[t] = 0;
    if (t == 127) out[0] = 0.0f;
}

__global__ __launch_bounds__(256)
void scatter_kernel(const int* __restrict__ ei, const int* __restrict__ types,
                    unsigned int* __restrict__ gcur,
                    unsigned short* __restrict__ entries, int E) {
    __shared__ unsigned int cnt[P];
    __shared__ unsigned int cur[P];
    const int tid = threadIdx.x;
    for (int p = tid; p < P; p += 256) cnt[p] = 0;
    __syncthreads();

    const int start = blockIdx.x * CHUNK;
    const int end   = min(start + CHUNK, E);

    // pass A: count endpoints per partition (LDS)
    for (int e = start + tid; e < end; e += 256) {
        atomicAdd(&cnt[((unsigned int)ei[e])     >> 9], 1u);
        atomicAdd(&cnt[((unsigned int)ei[E + e]) >> 9], 1u);
    }
    __syncthreads();

    // reserve contiguous range per partition: one global atomic per (block, partition)
    for (int p = tid; p < P; p += 256)
        cur[p] = cnt[p] ? atomicAdd(&gcur[p], cnt[p]) : 0u;
    __syncthreads();

    // pass B: scatter packed u16 entries via LDS cursors
    for (int e = start + tid; e < end; e += 256) {
        const unsigned int s  = (unsigned int)ei[e];
        const unsigned int d  = (unsigned int)ei[E + e];
        const unsigned int ts = (unsigned int)types[s];
        const unsigned int td = (unsigned int)types[d];
        const unsigned int ps = atomicAdd(&cur[s >> 9], 1u);
        entries[ps] = (unsigned short)(((s & 511u) << 5) | td);           // out @ src
        const unsigned int pd = atomicAdd(&cur[d >> 9], 1u);
        entries[pd] = (unsigned short)(((d & 511u) << 5) | 0x10u | ts);   // in  @ dst
    }
}

__global__ __launch_bounds__(256)
void hist_list_kernel(const unsigned short* __restrict__ entries,
                      const unsigned int* __restrict__ gcur,
                      const int* __restrict__ types,
                      unsigned int* __restrict__ pk,
                      int* __restrict__ tcnt, int* __restrict__ tlist, int N) {
    __shared__ unsigned int hist[NODE_P * NT];   // 32 KB
    __shared__ int lcnt[NT], lbase[NT];
    const int tid = threadIdx.x;
    const int p   = blockIdx.x;

    for (int i = tid; i < NODE_P * NT; i += 256) hist[i] = 0;
    if (tid < NT) lcnt[tid] = 0;
    __syncthreads();

    // histogram this partition's contiguous entry run
    const unsigned int start = (unsigned int)p * CAP;
    const unsigned int end   = min(gcur[p], (unsigned int)(p + 1) * CAP);
    for (unsigned int i = start + tid; i < end; i += 256) {
        const unsigned int e = entries[i];
        atomicAdd(&hist[(e >> 5) * NT + (e & 15u)], (e & 0x10u) ? 0x10000u : 1u);
    }

    // fused list build for this partition's 512 nodes
    const int n0 = p * NODE_P;
    const int nn = min(NODE_P, N - n0);
    int ty0 = -1, ty1 = -1, r0i = 0, r1i = 0;
    if (tid < nn)       { ty0 = types[n0 + tid];       r0i = atomicAdd(&lcnt[ty0], 1); }
    if (tid + 256 < nn) { ty1 = types[n0 + tid + 256]; r1i = atomicAdd(&lcnt[ty1], 1); }
    __syncthreads();

    if (tid < NT) lbase[tid] = atomicAdd(&tcnt[tid], lcnt[tid]);
    __syncthreads();

    if (ty0 >= 0) tlist[ty0 * NNODES_C + lbase[ty0] + r0i] = n0 + tid;
    if (ty1 >= 0) tlist[ty1 * NNODES_C + lbase[ty1] + r1i] = n0 + tid + 256;

    unsigned int* dst = pk + (size_t)n0 * NT;
    for (int i = tid; i < nn * NT; i += 256) dst[i] = hist[i];
}

// ---------- fallback edge kernel (global atomics) ----------

__global__ __launch_bounds__(256)
void edge_kernel(const int* __restrict__ ei, const int* __restrict__ types,
                 unsigned int* __restrict__ pk, int E) {
    const int i = (blockIdx.x * blockDim.x + threadIdx.x) * 4;
    if (i >= E) return;
    if (i + 3 < E) {
        const int4 s4 = *reinterpret_cast<const int4*>(ei + i);
        const int4 t4 = *reinterpret_cast<const int4*>(ei + E + i);
        const int ss[4] = {s4.x, s4.y, s4.z, s4.w};
        const int tt[4] = {t4.x, t4.y, t4.z, t4.w};
        #pragma unroll
        for (int k = 0; k < 4; ++k) {
            atomicAdd(&pk[ss[k] * NT + types[tt[k]]], 1u);
            atomicAdd(&pk[tt[k] * NT + types[ss[k]]], 0x10000u);
        }
    } else {
        for (int e = i; e < E; ++e) {
            const int s = ei[e];
            const int t = ei[E + e];
            atomicAdd(&pk[s * NT + types[t]], 1u);
            atomicAdd(&pk[t * NT + types[s]], 0x10000u);
        }
    }
}

__global__ __launch_bounds__(256)
void list_kernel(const int* __restrict__ types,
                 int* __restrict__ tcnt, int* __restrict__ tlist, int N) {
    __shared__ int lcnt[NT];
    __shared__ int lbase[NT];
    if (threadIdx.x < NT) lcnt[threadIdx.x] = 0;
    __syncthreads();
    const int n = blockIdx.x * 256 + threadIdx.x;
    int ty = 0, lr = 0;
    const bool valid = (n < N);
    if (valid) {
        ty = types[n];
        lr = atomicAdd(&lcnt[ty], 1);
    }
    __syncthreads();
    if (threadIdx.x < NT)
        lbase[threadIdx.x] = atomicAdd(&tcnt[threadIdx.x], lcnt[threadIdx.x]);
    __syncthreads();
    if (valid)
        tlist[ty * NNODES_C + lbase[ty] + lr] = n;
}

// ---------- node kernel (R6 structure) ----------

__global__ __launch_bounds__(256)
void node_kernel(const float* __restrict__ reps,
                 const float* __restrict__ rmaps,
                 const unsigned int* __restrict__ pk,
                 const int* __restrict__ tcnt,
                 const int* __restrict__ tlist,
                 float* __restrict__ out, int N) {
    const int ty  = blockIdx.y;
    const int cnt = tcnt[ty];
    if ((int)(blockIdx.x * 64) >= cnt) return;

    const int tid = threadIdx.x;
    const int w   = tid >> 6;
    const int l   = tid & 63;
    const int tg  = l >> 4;
    const int r   = l & 15;

    float4 Rf[4][4];
    {
        const float* Rbase = rmaps + (((size_t)ty * NT + tg * 4) * D + r) * D;
        #pragma unroll
        for (int jt = 0; jt < 4; ++jt)
            #pragma unroll
            for (int q = 0; q < 4; ++q)
                Rf[jt][q] = *reinterpret_cast<const float4*>(Rbase + jt * D * D + q * 4);
    }

    __shared__ int   NI[64];
    __shared__ float X[64][16];
    __shared__ float C[64][16];
    __shared__ int   PD[64][4];
    __shared__ float IDG[64];

    float part = 0.0f;

    for (int base = blockIdx.x * 64; base < cnt; base += gridDim.x * 64) {
        const int nb = min(64, cnt - base);

        __syncthreads();
        if (tid < nb) NI[tid] = tlist[ty * NNODES_C + base + tid];
        __syncthreads();

        const int b = tid >> 2, q = tid & 3;
        if (b < nb) {
            const int n = NI[b];
            const uint4 pw = reinterpret_cast<const uint4*>(pk + (size_t)n * NT)[q];
            const unsigned int ws4[4] = {pw.x, pw.y, pw.z, pw.w};
            int hsum = 0;
            #pragma unroll
            for (int j = 0; j < 4; ++j) {
                const int hi = (int)(ws4[j] >> 16);
                const int lo = (int)(ws4[j] & 0xFFFFu);
                C[b][q * 4 + j] = (float)(lo - hi);
                hsum += hi;
            }
            PD[b][q] = hsum;
            #pragma unroll
            for (int j = 0; j < 4; ++j)
                X[b][q * 4 + j] = reps[(q * 4 + j) * N + n];
        }
        __syncthreads();
        if (tid < nb) {
            const int dg = PD[tid][0] + PD[tid][1] + PD[tid][2] + PD[tid][3];
            IDG[tid] = (dg > 0) ? (1.0f / (float)dg) : 0.0f;
        }
        __syncthreads();

        for (int bb = w; bb < nb; bb += 4) {
            const float4 x0 = *reinterpret_cast<const float4*>(&X[bb][0]);
            const float4 x1 = *reinterpret_cast<const float4*>(&X[bb][4]);
            const float4 x2 = *reinterpret_cast<const float4*>(&X[bb][8]);
            const float4 x3 = *reinterpret_cast<const float4*>(&X[bb][12]);
            const float4 c4 = *reinterpret_cast<const float4*>(&C[bb][tg * 4]);
            const float idg = IDG[bb];
            const float ca[4] = {c4.x, c4.y, c4.z, c4.w};

            float y = 0.0f;
            #pragma unroll
            for (int jt = 0; jt < 4; ++jt) {
                float s = 0.0f;
                s = fmaf(Rf[jt][0].x, x0.x, s); s = fmaf(Rf[jt][0].y, x0.y, s);
                s = fmaf(Rf[jt][0].z, x0.z, s); s = fmaf(Rf[jt][0].w, x0.w, s);
                s = fmaf(Rf[jt][1].x, x1.x, s); s = fmaf(Rf[jt][1].y, x1.y, s);
                s = fmaf(Rf[jt][1].z, x1.z, s); s = fmaf(Rf[jt][1].w, x1.w, s);
                s = fmaf(Rf[jt][2].x, x2.x, s); s = fmaf(Rf[jt][2].y, x2.y, s);
                s = fmaf(Rf[jt][2].z, x2.z, s); s = fmaf(Rf[jt][2].w, x2.w, s);
                s = fmaf(Rf[jt][3].x, x3.x, s); s = fmaf(Rf[jt][3].y, x3.y, s);
                s = fmaf(Rf[jt][3].z, x3.z, s); s = fmaf(Rf[jt][3].w, x3.w, s);
                y = fmaf(ca[jt], s, y);
            }
            y += __shfl_xor(y, 16);
            y += __shfl_xor(y, 32);
            if (l < 16) part = fmaf(y * y, idg, part);
        }
    }

    #pragma unroll
    for (int off = 32; off > 0; off >>= 1)
        part += __shfl_down(part, off);
    __shared__ float wpart[4];
    const int lane = threadIdx.x & 63;
    const int wid  = threadIdx.x >> 6;
    if (lane == 0) wpart[wid] = part;
    __syncthreads();
    if (threadIdx.x == 0) {
        const float v = wpart[0] + wpart[1] + wpart[2] + wpart[3];
        if (v != 0.0f) atomicAdd(out, v);
    }
}

extern "C" void kernel_launch(void* const* d_in, const int* in_sizes, int n_in,
                              void* d_out, int out_size, void* d_ws, size_t ws_size,
                              hipStream_t stream) {
    const float* reps  = (const float*)d_in[0];   // [16, N]
    const float* rmaps = (const float*)d_in[1];   // [16,16,16,16]
    const int*   ei    = (const int*)d_in[2];     // [2, E]
    const int*   types = (const int*)d_in[3];     // [N]
    float* out = (float*)d_out;

    const int E = in_sizes[2] / 2;
    const int N = in_sizes[3];

    char* ws = (char*)d_ws;
    const bool fast = (N == NNODES_C && E == E_C && ws_size >= WS_NEED);

    if (fast) {
        unsigned short* entries = (unsigned short*)(ws + OFF_ENT);
        unsigned int*   pk      = (unsigned int*)(ws + OFF_PK);
        unsigned int*   gcur    = (unsigned int*)(ws + OFF_GCUR);
        int* tcnt  = (int*)(ws + OFF_TCNT);
        int* tlist = (int*)(ws + OFF_TLIST);

        init_kernel     <<<1,    128, 0, stream>>>(gcur, tcnt, out);
        scatter_kernel  <<<NBLK, 256, 0, stream>>>(ei, types, gcur, entries, E);
        hist_list_kernel<<<P,    256, 0, stream>>>(entries, gcur, types, pk,
                                                   tcnt, tlist, N);
        dim3 grid(52, NT);
        node_kernel<<<grid, 256, 0, stream>>>(reps, rmaps, pk, tcnt, tlist, out, N);
    } else {
        unsigned int* pk = (unsigned int*)ws;
        int* tcnt  = (int*)(ws + F_TCNT);
        int* tlist = (int*)(ws + F_TLIST);

        hipMemsetAsync(d_ws, 0, F_TLIST, stream);
        hipMemsetAsync(d_out, 0, sizeof(float), stream);
        edge_kernel<<<(E / 4 + 255) / 256, 256, 0, stream>>>(ei, types, pk, E);
        list_kernel<<<(N + 255) / 256, 256, 0, stream>>>(types, tcnt, tlist, N);
        dim3 grid(52, NT);
        node_kernel<<<grid, 256, 0, stream>>>(reps, rmaps, pk, tcnt, tlist, out, N);
    }
}

// Round 10
// 60.596 us; speedup vs baseline: 1.8551x; 1.2310x over previous
//
#include <hip/hip_runtime.h>

constexpr int NNODES_C = 50000;
constexpr int D = 16;
constexpr int NT = 16;
constexpr int E_C = 800000;

// ---- fast path constants ----
constexpr int NODE_P = 256;              // nodes per partition
constexpr int NPART  = 196;              // ceil(50000/256)
constexpr int SLOT   = 128;              // u16 slots per (block,partition); fill ~52+-7
constexpr int CHUNK  = 5120;             // edges per scatter block
constexpr int NBLK   = 157;              // ceil(800000/5120)
constexpr int CAP_E  = NBLK * SLOT;      // 20096 entries per partition
constexpr int CNT_PITCH = 160;           // padded pitch for cnt_g[p][b]

// fast ws layout:
//   entries: u16[NPART*CAP_E]      @ 0          (7,877,632 B)
//   cnt_g  : u32[NPART*CNT_PITCH]  @ 7,877,632  (125,440 B)
constexpr size_t OFF_ENT   = 0;
constexpr size_t OFF_CNT   = (size_t)NPART * CAP_E * 2;
constexpr size_t FAST_NEED = OFF_CNT + (size_t)NPART * CNT_PITCH * 4;

// ---- fallback (R6) layout: pk @0, tcnt @3.2M, tlist @3.2M+64 ----
constexpr size_t F_TCNT  = 3200000;
constexpr size_t F_TLIST = 3200064;

// entry packing: (node&255)<<5 | dir<<4 | type   (dir=1: in-edge at dst)

// ---------- fast path ----------

__global__ __launch_bounds__(256)
void scatter_kernel(const int* __restrict__ ei, const int* __restrict__ types,
                    unsigned short* __restrict__ entries,
                    unsigned int* __restrict__ cnt_g, int E) {
    __shared__ unsigned int cur[NPART];
    const int tid = threadIdx.x;
    const int b   = blockIdx.x;
    for (int p = tid; p < NPART; p += 256)
        cur[p] = (unsigned int)p * CAP_E + (unsigned int)b * SLOT;
    __syncthreads();

    const int start = b * CHUNK;
    const int end   = min(start + CHUNK, E);
    for (int e = start + tid; e < end; e += 256) {
        const unsigned int s  = (unsigned int)ei[e];
        const unsigned int d  = (unsigned int)ei[E + e];
        const unsigned int ts = (unsigned int)types[s];
        const unsigned int td = (unsigned int)types[d];
        const unsigned int ps = atomicAdd(&cur[s >> 8], 1u);
        entries[ps] = (unsigned short)(((s & 255u) << 5) | td);           // out @ src
        const unsigned int pd = atomicAdd(&cur[d >> 8], 1u);
        entries[pd] = (unsigned short)(((d & 255u) << 5) | 0x10u | ts);   // in  @ dst
    }
    __syncthreads();
    for (int p = tid; p < NPART; p += 256)
        cnt_g[p * CNT_PITCH + b] =
            cur[p] - ((unsigned int)p * CAP_E + (unsigned int)b * SLOT);
}

// One block per 256-node partition: LDS histogram -> in-place float C + 1/deg,
// coalesced X staging, per-type node lists, R[ty]-in-registers consume.
__global__ __launch_bounds__(512)
void hist_node_kernel(const float* __restrict__ reps,
                      const float* __restrict__ rmaps,
                      const unsigned short* __restrict__ entries,
                      const unsigned int* __restrict__ cnt_g,
                      const int* __restrict__ types,
                      float* __restrict__ out, int N) {
    __shared__ unsigned int  hist[NODE_P * NT];   // 16 KB; reused as float C
    __shared__ float         X[NODE_P][16];       // 16 KB
    __shared__ unsigned char llist[NT * NODE_P];  // 4 KB
    __shared__ float         IDG[NODE_P];         // 1 KB
    __shared__ int           lcnt[NT];
    __shared__ unsigned int  cnt_s[NBLK];
    __shared__ float         wpart[8];

    const int tid = threadIdx.x;
    const int p   = blockIdx.x;
    const int n0  = p * NODE_P;
    const int nn  = min(NODE_P, N - n0);

    for (int i = tid; i < NODE_P * NT; i += 512) hist[i] = 0u;
    if (tid < NT)   lcnt[tid]  = 0;
    if (tid < NBLK) cnt_s[tid] = cnt_g[p * CNT_PITCH + tid];
    __syncthreads();

    // slot histogram: 2 threads per slot, uint4-vectorized entry reads
    if (tid < 2 * NBLK) {
        const int slot = tid >> 1;
        const unsigned int cnt = cnt_s[slot];
        const uint4* src = reinterpret_cast<const uint4*>(
            entries + (size_t)p * CAP_E + slot * SLOT);
        const int nch = (int)((cnt + 7) >> 3);
        for (int c = (tid & 1); c < nch; c += 2) {
            const uint4 v = src[c];
            const unsigned int words[4] = {v.x, v.y, v.z, v.w};
            const unsigned int base = (unsigned int)c * 8;
            #pragma unroll
            for (int k = 0; k < 4; ++k) {
                #pragma unroll
                for (int h = 0; h < 2; ++h) {
                    const unsigned int idx = base + k * 2 + h;
                    if (idx < cnt) {
                        const unsigned int e = (words[k] >> (h * 16)) & 0xFFFFu;
                        atomicAdd(&hist[(e >> 5) * NT + (e & 15u)],
                                  (e & 0x10u) ? 0x10000u : 1u);
                    }
                }
            }
        }
    }
    // X staging: coalesced (256 consecutive nodes per row), 8 rows per thread-half
    {
        const int half = tid >> 8;        // 0 or 1
        const int tt   = tid & 255;
        if (tt < nn) {
            #pragma unroll
            for (int j = 0; j < 8; ++j)
                X[tt][half * 8 + j] = reps[(half * 8 + j) * N + n0 + tt];
        }
    }
    __syncthreads();

    // per-node: deg, in-place C floats, type-list insert (each thread owns row tid)
    if (tid < nn) {
        unsigned int deg = 0;
        #pragma unroll
        for (int t = 0; t < NT; ++t) deg += (hist[tid * NT + t] >> 16);
        #pragma unroll
        for (int t = 0; t < NT; ++t) {
            const unsigned int hw = hist[tid * NT + t];
            const float c = (float)((int)(hw & 0xFFFFu) - (int)(hw >> 16));
            hist[tid * NT + t] = __float_as_uint(c);
        }
        IDG[tid] = (deg > 0) ? (1.0f / (float)deg) : 0.0f;
        const int ty = types[n0 + tid];
        const int rk = atomicAdd(&lcnt[ty], 1);
        llist[ty * NODE_P + rk] = (unsigned char)tid;
    }
    __syncthreads();

    // consume: lane l = (tg = l>>4, r = l&15); wave wv takes list entries wv, wv+8, ...
    const int wv = tid >> 6;
    const int l  = tid & 63;
    const int tg = l >> 4;
    const int r  = l & 15;
    const float* __restrict__ C_f = (const float*)hist;

    float part = 0.0f;
    for (int ty = 0; ty < NT; ++ty) {
        const int m = lcnt[ty];
        if (m == 0) continue;

        float4 Rf[4][4];
        const float* Rbase = rmaps + (((size_t)ty * NT + tg * 4) * D + r) * D;
        #pragma unroll
        for (int jt = 0; jt < 4; ++jt)
            #pragma unroll
            for (int q = 0; q < 4; ++q)
                Rf[jt][q] = *reinterpret_cast<const float4*>(Rbase + jt * D * D + q * 4);

        for (int idx = wv; idx < m; idx += 8) {
            const int nl = llist[ty * NODE_P + idx];
            const float4 x0 = *reinterpret_cast<const float4*>(&X[nl][0]);
            const float4 x1 = *reinterpret_cast<const float4*>(&X[nl][4]);
            const float4 x2 = *reinterpret_cast<const float4*>(&X[nl][8]);
            const float4 x3 = *reinterpret_cast<const float4*>(&X[nl][12]);
            const float4 c4 = *reinterpret_cast<const float4*>(&C_f[nl * NT + tg * 4]);
            const float idg = IDG[nl];
            const float ca[4] = {c4.x, c4.y, c4.z, c4.w};

            float y = 0.0f;
            #pragma unroll
            for (int jt = 0; jt < 4; ++jt) {
                float s = 0.0f;
                s = fmaf(Rf[jt][0].x, x0.x, s); s = fmaf(Rf[jt][0].y, x0.y, s);
                s = fmaf(Rf[jt][0].z, x0.z, s); s = fmaf(Rf[jt][0].w, x0.w, s);
                s = fmaf(Rf[jt][1].x, x1.x, s); s = fmaf(Rf[jt][1].y, x1.y, s);
                s = fmaf(Rf[jt][1].z, x1.z, s); s = fmaf(Rf[jt][1].w, x1.w, s);
                s = fmaf(Rf[jt][2].x, x2.x, s); s = fmaf(Rf[jt][2].y, x2.y, s);
                s = fmaf(Rf[jt][2].z, x2.z, s); s = fmaf(Rf[jt][2].w, x2.w, s);
                s = fmaf(Rf[jt][3].x, x3.x, s); s = fmaf(Rf[jt][3].y, x3.y, s);
                s = fmaf(Rf[jt][3].z, x3.z, s); s = fmaf(Rf[jt][3].w, x3.w, s);
                y = fmaf(ca[jt], s, y);
            }
            y += __shfl_xor(y, 16);
            y += __shfl_xor(y, 32);
            if (l < 16) part = fmaf(y * y, idg, part);
        }
    }

    #pragma unroll
    for (int off = 32; off > 0; off >>= 1)
        part += __shfl_down(part, off);
    if (l == 0) wpart[wv] = part;
    __syncthreads();
    if (tid == 0) {
        float v = 0.0f;
        #pragma unroll
        for (int i = 0; i < 8; ++i) v += wpart[i];
        if (v != 0.0f) atomicAdd(out, v);
    }
}

// ---------- fallback path (R6 structure, shape-generic) ----------

__global__ __launch_bounds__(256)
void edge_kernel(const int* __restrict__ ei, const int* __restrict__ types,
                 unsigned int* __restrict__ pk, int E) {
    const int i = (blockIdx.x * blockDim.x + threadIdx.x) * 4;
    if (i >= E) return;
    if (i + 3 < E) {
        const int4 s4 = *reinterpret_cast<const int4*>(ei + i);
        const int4 t4 = *reinterpret_cast<const int4*>(ei + E + i);
        const int ss[4] = {s4.x, s4.y, s4.z, s4.w};
        const int tt[4] = {t4.x, t4.y, t4.z, t4.w};
        #pragma unroll
        for (int k = 0; k < 4; ++k) {
            atomicAdd(&pk[ss[k] * NT + types[tt[k]]], 1u);
            atomicAdd(&pk[tt[k] * NT + types[ss[k]]], 0x10000u);
        }
    } else {
        for (int e = i; e < E; ++e) {
            const int s = ei[e];
            const int t = ei[E + e];
            atomicAdd(&pk[s * NT + types[t]], 1u);
            atomicAdd(&pk[t * NT + types[s]], 0x10000u);
        }
    }
}

__global__ __launch_bounds__(256)
void list_kernel(const int* __restrict__ types,
                 int* __restrict__ tcnt, int* __restrict__ tlist, int N) {
    __shared__ int lcnt[NT];
    __shared__ int lbase[NT];
    if (threadIdx.x < NT) lcnt[threadIdx.x] = 0;
    __syncthreads();
    const int n = blockIdx.x * 256 + threadIdx.x;
    int ty = 0, lr = 0;
    const bool valid = (n < N);
    if (valid) {
        ty = types[n];
        lr = atomicAdd(&lcnt[ty], 1);
    }
    __syncthreads();
    if (threadIdx.x < NT)
        lbase[threadIdx.x] = atomicAdd(&tcnt[threadIdx.x], lcnt[threadIdx.x]);
    __syncthreads();
    if (valid)
        tlist[ty * NNODES_C + lbase[ty] + lr] = n;
}

__global__ __launch_bounds__(256)
void node_kernel(const float* __restrict__ reps,
                 const float* __restrict__ rmaps,
                 const unsigned int* __restrict__ pk,
                 const int* __restrict__ tcnt,
                 const int* __restrict__ tlist,
                 float* __restrict__ out, int N) {
    const int ty  = blockIdx.y;
    const int cnt = tcnt[ty];
    if ((int)(blockIdx.x * 64) >= cnt) return;

    const int tid = threadIdx.x;
    const int w   = tid >> 6;
    const int l   = tid & 63;
    const int tg  = l >> 4;
    const int r   = l & 15;

    float4 Rf[4][4];
    {
        const float* Rbase = rmaps + (((size_t)ty * NT + tg * 4) * D + r) * D;
        #pragma unroll
        for (int jt = 0; jt < 4; ++jt)
            #pragma unroll
            for (int q = 0; q < 4; ++q)
                Rf[jt][q] = *reinterpret_cast<const float4*>(Rbase + jt * D * D + q * 4);
    }

    __shared__ int   NI[64];
    __shared__ float X[64][16];
    __shared__ float C[64][16];
    __shared__ int   PD[64][4];
    __shared__ float IDG[64];

    float part = 0.0f;

    for (int base = blockIdx.x * 64; base < cnt; base += gridDim.x * 64) {
        const int nb = min(64, cnt - base);

        __syncthreads();
        if (tid < nb) NI[tid] = tlist[ty * NNODES_C + base + tid];
        __syncthreads();

        const int b = tid >> 2, q = tid & 3;
        if (b < nb) {
            const int n = NI[b];
            const uint4 pw = reinterpret_cast<const uint4*>(pk + (size_t)n * NT)[q];
            const unsigned int ws4[4] = {pw.x, pw.y, pw.z, pw.w};
            int hsum = 0;
            #pragma unroll
            for (int j = 0; j < 4; ++j) {
                const int hi = (int)(ws4[j] >> 16);
                const int lo = (int)(ws4[j] & 0xFFFFu);
                C[b][q * 4 + j] = (float)(lo - hi);
                hsum += hi;
            }
            PD[b][q] = hsum;
            #pragma unroll
            for (int j = 0; j < 4; ++j)
                X[b][q * 4 + j] = reps[(q * 4 + j) * N + n];
        }
        __syncthreads();
        if (tid < nb) {
            const int dg = PD[tid][0] + PD[tid][1] + PD[tid][2] + PD[tid][3];
            IDG[tid] = (dg > 0) ? (1.0f / (float)dg) : 0.0f;
        }
        __syncthreads();

        for (int bb = w; bb < nb; bb += 4) {
            const float4 x0 = *reinterpret_cast<const float4*>(&X[bb][0]);
            const float4 x1 = *reinterpret_cast<const float4*>(&X[bb][4]);
            const float4 x2 = *reinterpret_cast<const float4*>(&X[bb][8]);
            const float4 x3 = *reinterpret_cast<const float4*>(&X[bb][12]);
            const float4 c4 = *reinterpret_cast<const float4*>(&C[bb][tg * 4]);
            const float idg = IDG[bb];
            const float ca[4] = {c4.x, c4.y, c4.z, c4.w};

            float y = 0.0f;
            #pragma unroll
            for (int jt = 0; jt < 4; ++jt) {
                float s = 0.0f;
                s = fmaf(Rf[jt][0].x, x0.x, s); s = fmaf(Rf[jt][0].y, x0.y, s);
                s = fmaf(Rf[jt][0].z, x0.z, s); s = fmaf(Rf[jt][0].w, x0.w, s);
                s = fmaf(Rf[jt][1].x, x1.x, s); s = fmaf(Rf[jt][1].y, x1.y, s);
                s = fmaf(Rf[jt][1].z, x1.z, s); s = fmaf(Rf[jt][1].w, x1.w, s);
                s = fmaf(Rf[jt][2].x, x2.x, s); s = fmaf(Rf[jt][2].y, x2.y, s);
                s = fmaf(Rf[jt][2].z, x2.z, s); s = fmaf(Rf[jt][2].w, x2.w, s);
                s = fmaf(Rf[jt][3].x, x3.x, s); s = fmaf(Rf[jt][3].y, x3.y, s);
                s = fmaf(Rf[jt][3].z, x3.z, s); s = fmaf(Rf[jt][3].w, x3.w, s);
                y = fmaf(ca[jt], s, y);
            }
            y += __shfl_xor(y, 16);
            y += __shfl_xor(y, 32);
            if (l < 16) part = fmaf(y * y, idg, part);
        }
    }

    #pragma unroll
    for (int off = 32; off > 0; off >>= 1)
        part += __shfl_down(part, off);
    __shared__ float wpart[4];
    if (l == 0) wpart[w] = part;
    __syncthreads();
    if (tid == 0) {
        const float v = wpart[0] + wpart[1] + wpart[2] + wpart[3];
        if (v != 0.0f) atomicAdd(out, v);
    }
}

extern "C" void kernel_launch(void* const* d_in, const int* in_sizes, int n_in,
                              void* d_out, int out_size, void* d_ws, size_t ws_size,
                              hipStream_t stream) {
    const float* reps  = (const float*)d_in[0];   // [16, N]
    const float* rmaps = (const float*)d_in[1];   // [16,16,16,16]
    const int*   ei    = (const int*)d_in[2];     // [2, E]
    const int*   types = (const int*)d_in[3];     // [N]
    float* out = (float*)d_out;

    const int E = in_sizes[2] / 2;
    const int N = in_sizes[3];

    char* ws = (char*)d_ws;
    const bool fast = (N == NNODES_C && E == E_C && ws_size >= FAST_NEED);

    hipMemsetAsync(d_out, 0, sizeof(float), stream);

    if (fast) {
        unsigned short* entries = (unsigned short*)(ws + OFF_ENT);
        unsigned int*   cnt_g   = (unsigned int*)(ws + OFF_CNT);

        scatter_kernel  <<<NBLK,  256, 0, stream>>>(ei, types, entries, cnt_g, E);
        hist_node_kernel<<<NPART, 512, 0, stream>>>(reps, rmaps, entries, cnt_g,
                                                    types, out, N);
    } else {
        unsigned int* pk = (unsigned int*)ws;
        int* tcnt  = (int*)(ws + F_TCNT);
        int* tlist = (int*)(ws + F_TLIST);

        hipMemsetAsync(d_ws, 0, F_TLIST, stream);
        edge_kernel<<<(E / 4 + 255) / 256, 256, 0, stream>>>(ei, types, pk, E);
        list_kernel<<<(N + 255) / 256, 256, 0, stream>>>(types, tcnt, tlist, N);
        dim3 grid(52, NT);
        node_kernel<<<grid, 256, 0, stream>>>(reps, rmaps, pk, tcnt, tlist, out, N);
    }
}

// Round 11
// 48.059 us; speedup vs baseline: 2.3391x; 1.2609x over previous
//
#include <hip/hip_runtime.h>

constexpr int NNODES_C = 50000;
constexpr int D = 16;
constexpr int NT = 16;
constexpr int E_C = 800000;

// ---- fast path constants ----
constexpr int NODE_P = 256;              // nodes per partition
constexpr int NPART  = 196;              // ceil(50000/256)
constexpr int SLOT   = 64;               // u16 slots per (block,partition); fill ~26+-5
constexpr int CHUNK  = 2560;             // edges per scatter block
constexpr int NBLK   = 313;              // ceil(800000/2560)
constexpr int CAP_E  = NBLK * SLOT;      // 20032 entries per partition
constexpr int CNT_PITCH = 320;           // padded pitch for cnt_g[p][b]

// fast ws layout:
//   entries: u16[NPART*CAP_E]      @ 0          (7,852,544 B)
//   cnt_g  : u32[NPART*CNT_PITCH]  @ 7,852,544  (250,880 B)
constexpr size_t OFF_ENT   = 0;
constexpr size_t OFF_CNT   = (size_t)NPART * CAP_E * 2;
constexpr size_t FAST_NEED = OFF_CNT + (size_t)NPART * CNT_PITCH * 4;

// ---- fallback (R6) layout: pk @0, tcnt @3.2M, tlist @3.2M+64 ----
constexpr size_t F_TCNT  = 3200000;
constexpr size_t F_TLIST = 3200064;

// entry packing: (node&255)<<5 | dir<<4 | type   (dir=1: in-edge at dst)

// ---------- fast path ----------

__global__ __launch_bounds__(256)
void scatter_kernel(const int* __restrict__ ei, const int* __restrict__ types,
                    unsigned short* __restrict__ entries,
                    unsigned int* __restrict__ cnt_g,
                    float* __restrict__ out, int E) {
    __shared__ unsigned int cur[NPART];
    const int tid = threadIdx.x;
    const int b   = blockIdx.x;
    if (b == 0 && tid == 0) out[0] = 0.0f;   // replaces memset dispatch
    for (int p = tid; p < NPART; p += 256)
        cur[p] = (unsigned int)p * CAP_E + (unsigned int)b * SLOT;
    __syncthreads();

    const int start = b * CHUNK;
    const int end   = min(start + CHUNK, E);
    for (int e = start + tid; e < end; e += 256) {
        const unsigned int s  = (unsigned int)ei[e];
        const unsigned int d  = (unsigned int)ei[E + e];
        const unsigned int ts = (unsigned int)types[s];
        const unsigned int td = (unsigned int)types[d];
        const unsigned int ps = atomicAdd(&cur[s >> 8], 1u);
        entries[ps] = (unsigned short)(((s & 255u) << 5) | td);           // out @ src
        const unsigned int pd = atomicAdd(&cur[d >> 8], 1u);
        entries[pd] = (unsigned short)(((d & 255u) << 5) | 0x10u | ts);   // in  @ dst
    }
    __syncthreads();
    for (int p = tid; p < NPART; p += 256)
        cnt_g[p * CNT_PITCH + b] =
            cur[p] - ((unsigned int)p * CAP_E + (unsigned int)b * SLOT);
}

// One block per 256-node partition: LDS histogram -> in-place float C + 1/deg,
// coalesced X staging, per-type node lists; consume with wave-owns-2-types
// (Rf loaded once per (wave,type), full wave per node).
__global__ __launch_bounds__(512)
void hist_node_kernel(const float* __restrict__ reps,
                      const float* __restrict__ rmaps,
                      const unsigned short* __restrict__ entries,
                      const unsigned int* __restrict__ cnt_g,
                      const int* __restrict__ types,
                      float* __restrict__ out, int N) {
    __shared__ unsigned int  hist[NODE_P * NT];   // 16 KB; reused as float C
    __shared__ float         X[NODE_P][16];       // 16 KB
    __shared__ unsigned char llist[NT * NODE_P];  // 4 KB
    __shared__ float         IDG[NODE_P];         // 1 KB
    __shared__ int           lcnt[NT];
    __shared__ unsigned int  cnt_s[NBLK];
    __shared__ float         wpart[8];

    const int tid = threadIdx.x;
    const int p   = blockIdx.x;
    const int n0  = p * NODE_P;
    const int nn  = min(NODE_P, N - n0);

    for (int i = tid; i < NODE_P * NT; i += 512) hist[i] = 0u;
    if (tid < NT)   lcnt[tid]  = 0;
    if (tid < NBLK) cnt_s[tid] = cnt_g[p * CNT_PITCH + tid];
    __syncthreads();

    // slot histogram: 1 thread per slot, uint4-vectorized entry reads
    if (tid < NBLK) {
        const unsigned int cnt = cnt_s[tid];
        const uint4* src = reinterpret_cast<const uint4*>(
            entries + (size_t)p * CAP_E + tid * SLOT);
        const int nch = (int)((cnt + 7) >> 3);
        for (int c = 0; c < nch; ++c) {
            const uint4 v = src[c];
            const unsigned int words[4] = {v.x, v.y, v.z, v.w};
            const unsigned int base = (unsigned int)c * 8;
            #pragma unroll
            for (int k = 0; k < 4; ++k) {
                #pragma unroll
                for (int h = 0; h < 2; ++h) {
                    const unsigned int idx = base + k * 2 + h;
                    if (idx < cnt) {
                        const unsigned int e = (words[k] >> (h * 16)) & 0xFFFFu;
                        atomicAdd(&hist[(e >> 5) * NT + (e & 15u)],
                                  (e & 0x10u) ? 0x10000u : 1u);
                    }
                }
            }
        }
    }
    // X staging: coalesced (256 consecutive nodes per row), 8 rows per thread-half
    {
        const int half = tid >> 8;        // 0 or 1
        const int tt   = tid & 255;
        if (tt < nn) {
            #pragma unroll
            for (int j = 0; j < 8; ++j)
                X[tt][half * 8 + j] = reps[(half * 8 + j) * N + n0 + tt];
        }
    }
    __syncthreads();

    // per-node: deg, in-place C floats, type-list insert (thread owns row tid)
    if (tid < nn) {
        unsigned int deg = 0;
        #pragma unroll
        for (int t = 0; t < NT; ++t) deg += (hist[tid * NT + t] >> 16);
        #pragma unroll
        for (int t = 0; t < NT; ++t) {
            const unsigned int hw = hist[tid * NT + t];
            const float c = (float)((int)(hw & 0xFFFFu) - (int)(hw >> 16));
            hist[tid * NT + t] = __float_as_uint(c);
        }
        IDG[tid] = (deg > 0) ? (1.0f / (float)deg) : 0.0f;
        const int ty = types[n0 + tid];
        const int rk = atomicAdd(&lcnt[ty], 1);
        llist[ty * NODE_P + rk] = (unsigned char)tid;
    }
    __syncthreads();

    // consume: wave wv owns types {2wv, 2wv+1}; lane l = (tg=l>>4, r=l&15)
    const int wv = tid >> 6;
    const int l  = tid & 63;
    const int tg = l >> 4;
    const int r  = l & 15;
    const float* __restrict__ C_f = (const float*)hist;

    float part = 0.0f;
    for (int ty = wv * 2; ty < wv * 2 + 2; ++ty) {
        const int m = lcnt[ty];
        if (m == 0) continue;

        float4 Rf[4][4];
        const float* Rbase = rmaps + (((size_t)ty * NT + tg * 4) * D + r) * D;
        #pragma unroll
        for (int jt = 0; jt < 4; ++jt)
            #pragma unroll
            for (int q = 0; q < 4; ++q)
                Rf[jt][q] = *reinterpret_cast<const float4*>(Rbase + jt * D * D + q * 4);

        for (int idx = 0; idx < m; ++idx) {
            const int nl = llist[ty * NODE_P + idx];
            const float4 x0 = *reinterpret_cast<const float4*>(&X[nl][0]);
            const float4 x1 = *reinterpret_cast<const float4*>(&X[nl][4]);
            const float4 x2 = *reinterpret_cast<const float4*>(&X[nl][8]);
            const float4 x3 = *reinterpret_cast<const float4*>(&X[nl][12]);
            const float4 c4 = *reinterpret_cast<const float4*>(&C_f[nl * NT + tg * 4]);
            const float idg = IDG[nl];
            const float ca[4] = {c4.x, c4.y, c4.z, c4.w};

            float y = 0.0f;
            #pragma unroll
            for (int jt = 0; jt < 4; ++jt) {
                float s = 0.0f;
                s = fmaf(Rf[jt][0].x, x0.x, s); s = fmaf(Rf[jt][0].y, x0.y, s);
                s = fmaf(Rf[jt][0].z, x0.z, s); s = fmaf(Rf[jt][0].w, x0.w, s);
                s = fmaf(Rf[jt][1].x, x1.x, s); s = fmaf(Rf[jt][1].y, x1.y, s);
                s = fmaf(Rf[jt][1].z, x1.z, s); s = fmaf(Rf[jt][1].w, x1.w, s);
                s = fmaf(Rf[jt][2].x, x2.x, s); s = fmaf(Rf[jt][2].y, x2.y, s);
                s = fmaf(Rf[jt][2].z, x2.z, s); s = fmaf(Rf[jt][2].w, x2.w, s);
                s = fmaf(Rf[jt][3].x, x3.x, s); s = fmaf(Rf[jt][3].y, x3.y, s);
                s = fmaf(Rf[jt][3].z, x3.z, s); s = fmaf(Rf[jt][3].w, x3.w, s);
                y = fmaf(ca[jt], s, y);
            }
            y += __shfl_xor(y, 16);
            y += __shfl_xor(y, 32);
            if (l < 16) part = fmaf(y * y, idg, part);
        }
    }

    #pragma unroll
    for (int off = 32; off > 0; off >>= 1)
        part += __shfl_down(part, off);
    if (l == 0) wpart[wv] = part;
    __syncthreads();
    if (tid == 0) {
        float v = 0.0f;
        #pragma unroll
        for (int i = 0; i < 8; ++i) v += wpart[i];
        if (v != 0.0f) atomicAdd(out, v);
    }
}

// ---------- fallback path (R6 structure, shape-generic) ----------

__global__ __launch_bounds__(256)
void edge_kernel(const int* __restrict__ ei, const int* __restrict__ types,
                 unsigned int* __restrict__ pk, int E) {
    const int i = (blockIdx.x * blockDim.x + threadIdx.x) * 4;
    if (i >= E) return;
    if (i + 3 < E) {
        const int4 s4 = *reinterpret_cast<const int4*>(ei + i);
        const int4 t4 = *reinterpret_cast<const int4*>(ei + E + i);
        const int ss[4] = {s4.x, s4.y, s4.z, s4.w};
        const int tt[4] = {t4.x, t4.y, t4.z, t4.w};
        #pragma unroll
        for (int k = 0; k < 4; ++k) {
            atomicAdd(&pk[ss[k] * NT + types[tt[k]]], 1u);
            atomicAdd(&pk[tt[k] * NT + types[ss[k]]], 0x10000u);
        }
    } else {
        for (int e = i; e < E; ++e) {
            const int s = ei[e];
            const int t = ei[E + e];
            atomicAdd(&pk[s * NT + types[t]], 1u);
            atomicAdd(&pk[t * NT + types[s]], 0x10000u);
        }
    }
}

__global__ __launch_bounds__(256)
void list_kernel(const int* __restrict__ types,
                 int* __restrict__ tcnt, int* __restrict__ tlist, int N) {
    __shared__ int lcnt[NT];
    __shared__ int lbase[NT];
    if (threadIdx.x < NT) lcnt[threadIdx.x] = 0;
    __syncthreads();
    const int n = blockIdx.x * 256 + threadIdx.x;
    int ty = 0, lr = 0;
    const bool valid = (n < N);
    if (valid) {
        ty = types[n];
        lr = atomicAdd(&lcnt[ty], 1);
    }
    __syncthreads();
    if (threadIdx.x < NT)
        lbase[threadIdx.x] = atomicAdd(&tcnt[threadIdx.x], lcnt[threadIdx.x]);
    __syncthreads();
    if (valid)
        tlist[ty * NNODES_C + lbase[ty] + lr] = n;
}

__global__ __launch_bounds__(256)
void node_kernel(const float* __restrict__ reps,
                 const float* __restrict__ rmaps,
                 const unsigned int* __restrict__ pk,
                 const int* __restrict__ tcnt,
                 const int* __restrict__ tlist,
                 float* __restrict__ out, int N) {
    const int ty  = blockIdx.y;
    const int cnt = tcnt[ty];
    if ((int)(blockIdx.x * 64) >= cnt) return;

    const int tid = threadIdx.x;
    const int w   = tid >> 6;
    const int l   = tid & 63;
    const int tg  = l >> 4;
    const int r   = l & 15;

    float4 Rf[4][4];
    {
        const float* Rbase = rmaps + (((size_t)ty * NT + tg * 4) * D + r) * D;
        #pragma unroll
        for (int jt = 0; jt < 4; ++jt)
            #pragma unroll
            for (int q = 0; q < 4; ++q)
                Rf[jt][q] = *reinterpret_cast<const float4*>(Rbase + jt * D * D + q * 4);
    }

    __shared__ int   NI[64];
    __shared__ float X[64][16];
    __shared__ float C[64][16];
    __shared__ int   PD[64][4];
    __shared__ float IDG[64];

    float part = 0.0f;

    for (int base = blockIdx.x * 64; base < cnt; base += gridDim.x * 64) {
        const int nb = min(64, cnt - base);

        __syncthreads();
        if (tid < nb) NI[tid] = tlist[ty * NNODES_C + base + tid];
        __syncthreads();

        const int b = tid >> 2, q = tid & 3;
        if (b < nb) {
            const int n = NI[b];
            const uint4 pw = reinterpret_cast<const uint4*>(pk + (size_t)n * NT)[q];
            const unsigned int ws4[4] = {pw.x, pw.y, pw.z, pw.w};
            int hsum = 0;
            #pragma unroll
            for (int j = 0; j < 4; ++j) {
                const int hi = (int)(ws4[j] >> 16);
                const int lo = (int)(ws4[j] & 0xFFFFu);
                C[b][q * 4 + j] = (float)(lo - hi);
                hsum += hi;
            }
            PD[b][q] = hsum;
            #pragma unroll
            for (int j = 0; j < 4; ++j)
                X[b][q * 4 + j] = reps[(q * 4 + j) * N + n];
        }
        __syncthreads();
        if (tid < nb) {
            const int dg = PD[tid][0] + PD[tid][1] + PD[tid][2] + PD[tid][3];
            IDG[tid] = (dg > 0) ? (1.0f / (float)dg) : 0.0f;
        }
        __syncthreads();

        for (int bb = w; bb < nb; bb += 4) {
            const float4 x0 = *reinterpret_cast<const float4*>(&X[bb][0]);
            const float4 x1 = *reinterpret_cast<const float4*>(&X[bb][4]);
            const float4 x2 = *reinterpret_cast<const float4*>(&X[bb][8]);
            const float4 x3 = *reinterpret_cast<const float4*>(&X[bb][12]);
            const float4 c4 = *reinterpret_cast<const float4*>(&C[bb][tg * 4]);
            const float idg = IDG[bb];
            const float ca[4] = {c4.x, c4.y, c4.z, c4.w};

            float y = 0.0f;
            #pragma unroll
            for (int jt = 0; jt < 4; ++jt) {
                float s = 0.0f;
                s = fmaf(Rf[jt][0].x, x0.x, s); s = fmaf(Rf[jt][0].y, x0.y, s);
                s = fmaf(Rf[jt][0].z, x0.z, s); s = fmaf(Rf[jt][0].w, x0.w, s);
                s = fmaf(Rf[jt][1].x, x1.x, s); s = fmaf(Rf[jt][1].y, x1.y, s);
                s = fmaf(Rf[jt][1].z, x1.z, s); s = fmaf(Rf[jt][1].w, x1.w, s);
                s = fmaf(Rf[jt][2].x, x2.x, s); s = fmaf(Rf[jt][2].y, x2.y, s);
                s = fmaf(Rf[jt][2].z, x2.z, s); s = fmaf(Rf[jt][2].w, x2.w, s);
                s = fmaf(Rf[jt][3].x, x3.x, s); s = fmaf(Rf[jt][3].y, x3.y, s);
                s = fmaf(Rf[jt][3].z, x3.z, s); s = fmaf(Rf[jt][3].w, x3.w, s);
                y = fmaf(ca[jt], s, y);
            }
            y += __shfl_xor(y, 16);
            y += __shfl_xor(y, 32);
            if (l < 16) part = fmaf(y * y, idg, part);
        }
    }

    #pragma unroll
    for (int off = 32; off > 0; off >>= 1)
        part += __shfl_down(part, off);
    __shared__ float wpart[4];
    if (l == 0) wpart[w] = part;
    __syncthreads();
    if (tid == 0) {
        const float v = wpart[0] + wpart[1] + wpart[2] + wpart[3];
        if (v != 0.0f) atomicAdd(out, v);
    }
}

extern "C" void kernel_launch(void* const* d_in, const int* in_sizes, int n_in,
                              void* d_out, int out_size, void* d_ws, size_t ws_size,
                              hipStream_t stream) {
    const float* reps  = (const float*)d_in[0];   // [16, N]
    const float* rmaps = (const float*)d_in[1];   // [16,16,16,16]
    const int*   ei    = (const int*)d_in[2];     // [2, E]
    const int*   types = (const int*)d_in[3];     // [N]
    float* out = (float*)d_out;

    const int E = in_sizes[2] / 2;
    const int N = in_sizes[3];

    char* ws = (char*)d_ws;
    const bool fast = (N == NNODES_C && E == E_C && ws_size >= FAST_NEED);

    if (fast) {
        unsigned short* entries = (unsigned short*)(ws + OFF_ENT);
        unsigned int*   cnt_g   = (unsigned int*)(ws + OFF_CNT);

        scatter_kernel  <<<NBLK,  256, 0, stream>>>(ei, types, entries, cnt_g, out, E);
        hist_node_kernel<<<NPART, 512, 0, stream>>>(reps, rmaps, entries, cnt_g,
                                                    types, out, N);
    } else {
        unsigned int* pk = (unsigned int*)ws;
        int* tcnt  = (int*)(ws + F_TCNT);
        int* tlist = (int*)(ws + F_TLIST);

        hipMemsetAsync(d_ws, 0, F_TLIST, stream);
        hipMemsetAsync(d_out, 0, sizeof(float), stream);
        edge_kernel<<<(E / 4 + 255) / 256, 256, 0, stream>>>(ei, types, pk, E);
        list_kernel<<<(N + 255) / 256, 256, 0, stream>>>(types, tcnt, tlist, N);
        dim3 grid(52, NT);
        node_kernel<<<grid, 256, 0, stream>>>(reps, rmaps, pk, tcnt, tlist, out, N);
    }
}

// Round 12
// 47.358 us; speedup vs baseline: 2.3737x; 1.0148x over previous
//
#include <hip/hip_runtime.h>

constexpr int NNODES_C = 50000;
constexpr int D = 16;
constexpr int NT = 16;
constexpr int E_C = 800000;

// ---- fast path constants ----
constexpr int NODE_P = 256;              // nodes per partition
constexpr int NPART  = 196;              // ceil(50000/256)
constexpr int SLOT   = 24;               // u16 slots per (block,partition); fill ~5.2+-2.3
constexpr int CHUNK  = 512;              // edges per scatter block
constexpr int NBLK   = 1563;             // ceil(800000/512)
constexpr int CAP_E  = NBLK * SLOT;      // 37512 entries per partition (48B-aligned slots)
constexpr int CNT_PITCH = 1568;          // padded pitch for cnt_g[p][b]

// fast ws layout:
//   entries: u16[NPART*CAP_E]      @ 0           (14,704,704 B)
//   cnt_g  : u32[NPART*CNT_PITCH]  @ 14,704,704  (1,229,312 B)
constexpr size_t OFF_ENT   = 0;
constexpr size_t OFF_CNT   = (size_t)NPART * CAP_E * 2;
constexpr size_t FAST_NEED = OFF_CNT + (size_t)NPART * CNT_PITCH * 4;

// ---- fallback (R6) layout: pk @0, tcnt @3.2M, tlist @3.2M+64 ----
constexpr size_t F_TCNT  = 3200000;
constexpr size_t F_TLIST = 3200064;

// entry packing: (node&255)<<5 | dir<<4 | type   (dir=1: in-edge at dst)

// ---------- fast path ----------

__device__ __forceinline__ void emit_edge(unsigned int s, unsigned int d,
                                          unsigned int ts, unsigned int td,
                                          unsigned int* cur,
                                          unsigned short* entries) {
    const unsigned int ps = atomicAdd(&cur[s >> 8], 1u);
    entries[ps] = (unsigned short)(((s & 255u) << 5) | td);           // out @ src
    const unsigned int pd = atomicAdd(&cur[d >> 8], 1u);
    entries[pd] = (unsigned short)(((d & 255u) << 5) | 0x10u | ts);   // in  @ dst
}

__global__ __launch_bounds__(256)
void scatter_kernel(const int* __restrict__ ei, const int* __restrict__ types,
                    unsigned short* __restrict__ entries,
                    unsigned int* __restrict__ cnt_g,
                    float* __restrict__ out, int E) {
    __shared__ unsigned int cur[NPART];
    const int tid = threadIdx.x;
    const int b   = blockIdx.x;
    if (b == 0 && tid == 0) out[0] = 0.0f;   // replaces memset dispatch
    if (tid < NPART)
        cur[tid] = (unsigned int)tid * CAP_E + (unsigned int)b * SLOT;
    __syncthreads();

    const int start = b * CHUNK;
    const int end   = min(start + CHUNK, E);
    const int e0    = start + tid;
    const int e1    = e0 + 256;

    if (e1 < end) {
        // both edges: issue all loads first for MLP
        const unsigned int s0 = (unsigned int)ei[e0];
        const unsigned int d0 = (unsigned int)ei[E + e0];
        const unsigned int s1 = (unsigned int)ei[e1];
        const unsigned int d1 = (unsigned int)ei[E + e1];
        const unsigned int ts0 = (unsigned int)types[s0];
        const unsigned int td0 = (unsigned int)types[d0];
        const unsigned int ts1 = (unsigned int)types[s1];
        const unsigned int td1 = (unsigned int)types[d1];
        emit_edge(s0, d0, ts0, td0, cur, entries);
        emit_edge(s1, d1, ts1, td1, cur, entries);
    } else if (e0 < end) {
        const unsigned int s0 = (unsigned int)ei[e0];
        const unsigned int d0 = (unsigned int)ei[E + e0];
        const unsigned int ts0 = (unsigned int)types[s0];
        const unsigned int td0 = (unsigned int)types[d0];
        emit_edge(s0, d0, ts0, td0, cur, entries);
    }
    __syncthreads();
    if (tid < NPART)
        cnt_g[tid * CNT_PITCH + b] =
            cur[tid] - ((unsigned int)tid * CAP_E + (unsigned int)b * SLOT);
}

// One block per 256-node partition: LDS histogram -> in-place float C + 1/deg,
// coalesced X staging, per-type node lists; consume with wave-owns-2-types.
__global__ __launch_bounds__(512)
void hist_node_kernel(const float* __restrict__ reps,
                      const float* __restrict__ rmaps,
                      const unsigned short* __restrict__ entries,
                      const unsigned int* __restrict__ cnt_g,
                      const int* __restrict__ types,
                      float* __restrict__ out, int N) {
    __shared__ unsigned int  hist[NODE_P * NT];   // 16 KB; reused as float C
    __shared__ float         X[NODE_P][16];       // 16 KB
    __shared__ unsigned char llist[NT * NODE_P];  // 4 KB
    __shared__ float         IDG[NODE_P];         // 1 KB
    __shared__ int           lcnt[NT];
    __shared__ unsigned int  cnt_s[NBLK];         // 6.3 KB
    __shared__ float         wpart[8];

    const int tid = threadIdx.x;
    const int p   = blockIdx.x;
    const int n0  = p * NODE_P;
    const int nn  = min(NODE_P, N - n0);

    for (int i = tid; i < NODE_P * NT; i += 512) hist[i] = 0u;
    if (tid < NT) lcnt[tid] = 0;
    for (int i = tid; i < NBLK; i += 512)
        cnt_s[i] = cnt_g[p * CNT_PITCH + i];
    __syncthreads();

    // slot histogram: ~3 slots per thread, uint4-vectorized entry reads
    for (int slot = tid; slot < NBLK; slot += 512) {
        const unsigned int cnt = cnt_s[slot];
        if (cnt == 0) continue;
        const uint4* src = reinterpret_cast<const uint4*>(
            entries + (size_t)p * CAP_E + slot * SLOT);
        const int nch = (int)((cnt + 7) >> 3);
        for (int c = 0; c < nch; ++c) {
            const uint4 v = src[c];
            const unsigned int words[4] = {v.x, v.y, v.z, v.w};
            const unsigned int base = (unsigned int)c * 8;
            #pragma unroll
            for (int k = 0; k < 4; ++k) {
                #pragma unroll
                for (int h = 0; h < 2; ++h) {
                    const unsigned int idx = base + k * 2 + h;
                    if (idx < cnt) {
                        const unsigned int e = (words[k] >> (h * 16)) & 0xFFFFu;
                        atomicAdd(&hist[(e >> 5) * NT + (e & 15u)],
                                  (e & 0x10u) ? 0x10000u : 1u);
                    }
                }
            }
        }
    }
    // X staging: coalesced (256 consecutive nodes per row), 8 rows per thread-half
    {
        const int half = tid >> 8;        // 0 or 1
        const int tt   = tid & 255;
        if (tt < nn) {
            #pragma unroll
            for (int j = 0; j < 8; ++j)
                X[tt][half * 8 + j] = reps[(half * 8 + j) * N + n0 + tt];
        }
    }
    __syncthreads();

    // per-node: deg, in-place C floats, type-list insert (thread owns row tid)
    if (tid < nn) {
        unsigned int deg = 0;
        #pragma unroll
        for (int t = 0; t < NT; ++t) deg += (hist[tid * NT + t] >> 16);
        #pragma unroll
        for (int t = 0; t < NT; ++t) {
            const unsigned int hw = hist[tid * NT + t];
            const float c = (float)((int)(hw & 0xFFFFu) - (int)(hw >> 16));
            hist[tid * NT + t] = __float_as_uint(c);
        }
        IDG[tid] = (deg > 0) ? (1.0f / (float)deg) : 0.0f;
        const int ty = types[n0 + tid];
        const int rk = atomicAdd(&lcnt[ty], 1);
        llist[ty * NODE_P + rk] = (unsigned char)tid;
    }
    __syncthreads();

    // consume: wave wv owns types {2wv, 2wv+1}; lane l = (tg=l>>4, r=l&15)
    const int wv = tid >> 6;
    const int l  = tid & 63;
    const int tg = l >> 4;
    const int r  = l & 15;
    const float* __restrict__ C_f = (const float*)hist;

    float part = 0.0f;
    for (int ty = wv * 2; ty < wv * 2 + 2; ++ty) {
        const int m = lcnt[ty];
        if (m == 0) continue;

        float4 Rf[4][4];
        const float* Rbase = rmaps + (((size_t)ty * NT + tg * 4) * D + r) * D;
        #pragma unroll
        for (int jt = 0; jt < 4; ++jt)
            #pragma unroll
            for (int q = 0; q < 4; ++q)
                Rf[jt][q] = *reinterpret_cast<const float4*>(Rbase + jt * D * D + q * 4);

        for (int idx = 0; idx < m; ++idx) {
            const int nl = llist[ty * NODE_P + idx];
            const float4 x0 = *reinterpret_cast<const float4*>(&X[nl][0]);
            const float4 x1 = *reinterpret_cast<const float4*>(&X[nl][4]);
            const float4 x2 = *reinterpret_cast<const float4*>(&X[nl][8]);
            const float4 x3 = *reinterpret_cast<const float4*>(&X[nl][12]);
            const float4 c4 = *reinterpret_cast<const float4*>(&C_f[nl * NT + tg * 4]);
            const float idg = IDG[nl];
            const float ca[4] = {c4.x, c4.y, c4.z, c4.w};

            float y = 0.0f;
            #pragma unroll
            for (int jt = 0; jt < 4; ++jt) {
                float s = 0.0f;
                s = fmaf(Rf[jt][0].x, x0.x, s); s = fmaf(Rf[jt][0].y, x0.y, s);
                s = fmaf(Rf[jt][0].z, x0.z, s); s = fmaf(Rf[jt][0].w, x0.w, s);
                s = fmaf(Rf[jt][1].x, x1.x, s); s = fmaf(Rf[jt][1].y, x1.y, s);
                s = fmaf(Rf[jt][1].z, x1.z, s); s = fmaf(Rf[jt][1].w, x1.w, s);
                s = fmaf(Rf[jt][2].x, x2.x, s); s = fmaf(Rf[jt][2].y, x2.y, s);
                s = fmaf(Rf[jt][2].z, x2.z, s); s = fmaf(Rf[jt][2].w, x2.w, s);
                s = fmaf(Rf[jt][3].x, x3.x, s); s = fmaf(Rf[jt][3].y, x3.y, s);
                s = fmaf(Rf[jt][3].z, x3.z, s); s = fmaf(Rf[jt][3].w, x3.w, s);
                y = fmaf(ca[jt], s, y);
            }
            y += __shfl_xor(y, 16);
            y += __shfl_xor(y, 32);
            if (l < 16) part = fmaf(y * y, idg, part);
        }
    }

    #pragma unroll
    for (int off = 32; off > 0; off >>= 1)
        part += __shfl_down(part, off);
    if (l == 0) wpart[wv] = part;
    __syncthreads();
    if (tid == 0) {
        float v = 0.0f;
        #pragma unroll
        for (int i = 0; i < 8; ++i) v += wpart[i];
        if (v != 0.0f) atomicAdd(out, v);
    }
}

// ---------- fallback path (R6 structure, shape-generic) ----------

__global__ __launch_bounds__(256)
void edge_kernel(const int* __restrict__ ei, const int* __restrict__ types,
                 unsigned int* __restrict__ pk, int E) {
    const int i = (blockIdx.x * blockDim.x + threadIdx.x) * 4;
    if (i >= E) return;
    if (i + 3 < E) {
        const int4 s4 = *reinterpret_cast<const int4*>(ei + i);
        const int4 t4 = *reinterpret_cast<const int4*>(ei + E + i);
        const int ss[4] = {s4.x, s4.y, s4.z, s4.w};
        const int tt[4] = {t4.x, t4.y, t4.z, t4.w};
        #pragma unroll
        for (int k = 0; k < 4; ++k) {
            atomicAdd(&pk[ss[k] * NT + types[tt[k]]], 1u);
            atomicAdd(&pk[tt[k] * NT + types[ss[k]]], 0x10000u);
        }
    } else {
        for (int e = i; e < E; ++e) {
            const int s = ei[e];
            const int t = ei[E + e];
            atomicAdd(&pk[s * NT + types[t]], 1u);
            atomicAdd(&pk[t * NT + types[s]], 0x10000u);
        }
    }
}

__global__ __launch_bounds__(256)
void list_kernel(const int* __restrict__ types,
                 int* __restrict__ tcnt, int* __restrict__ tlist, int N) {
    __shared__ int lcnt[NT];
    __shared__ int lbase[NT];
    if (threadIdx.x < NT) lcnt[threadIdx.x] = 0;
    __syncthreads();
    const int n = blockIdx.x * 256 + threadIdx.x;
    int ty = 0, lr = 0;
    const bool valid = (n < N);
    if (valid) {
        ty = types[n];
        lr = atomicAdd(&lcnt[ty], 1);
    }
    __syncthreads();
    if (threadIdx.x < NT)
        lbase[threadIdx.x] = atomicAdd(&tcnt[threadIdx.x], lcnt[threadIdx.x]);
    __syncthreads();
    if (valid)
        tlist[ty * NNODES_C + lbase[ty] + lr] = n;
}

__global__ __launch_bounds__(256)
void node_kernel(const float* __restrict__ reps,
                 const float* __restrict__ rmaps,
                 const unsigned int* __restrict__ pk,
                 const int* __restrict__ tcnt,
                 const int* __restrict__ tlist,
                 float* __restrict__ out, int N) {
    const int ty  = blockIdx.y;
    const int cnt = tcnt[ty];
    if ((int)(blockIdx.x * 64) >= cnt) return;

    const int tid = threadIdx.x;
    const int w   = tid >> 6;
    const int l   = tid & 63;
    const int tg  = l >> 4;
    const int r   = l & 15;

    float4 Rf[4][4];
    {
        const float* Rbase = rmaps + (((size_t)ty * NT + tg * 4) * D + r) * D;
        #pragma unroll
        for (int jt = 0; jt < 4; ++jt)
            #pragma unroll
            for (int q = 0; q < 4; ++q)
                Rf[jt][q] = *reinterpret_cast<const float4*>(Rbase + jt * D * D + q * 4);
    }

    __shared__ int   NI[64];
    __shared__ float X[64][16];
    __shared__ float C[64][16];
    __shared__ int   PD[64][4];
    __shared__ float IDG[64];

    float part = 0.0f;

    for (int base = blockIdx.x * 64; base < cnt; base += gridDim.x * 64) {
        const int nb = min(64, cnt - base);

        __syncthreads();
        if (tid < nb) NI[tid] = tlist[ty * NNODES_C + base + tid];
        __syncthreads();

        const int b = tid >> 2, q = tid & 3;
        if (b < nb) {
            const int n = NI[b];
            const uint4 pw = reinterpret_cast<const uint4*>(pk + (size_t)n * NT)[q];
            const unsigned int ws4[4] = {pw.x, pw.y, pw.z, pw.w};
            int hsum = 0;
            #pragma unroll
            for (int j = 0; j < 4; ++j) {
                const int hi = (int)(ws4[j] >> 16);
                const int lo = (int)(ws4[j] & 0xFFFFu);
                C[b][q * 4 + j] = (float)(lo - hi);
                hsum += hi;
            }
            PD[b][q] = hsum;
            #pragma unroll
            for (int j = 0; j < 4; ++j)
                X[b][q * 4 + j] = reps[(q * 4 + j) * N + n];
        }
        __syncthreads();
        if (tid < nb) {
            const int dg = PD[tid][0] + PD[tid][1] + PD[tid][2] + PD[tid][3];
            IDG[tid] = (dg > 0) ? (1.0f / (float)dg) : 0.0f;
        }
        __syncthreads();

        for (int bb = w; bb < nb; bb += 4) {
            const float4 x0 = *reinterpret_cast<const float4*>(&X[bb][0]);
            const float4 x1 = *reinterpret_cast<const float4*>(&X[bb][4]);
            const float4 x2 = *reinterpret_cast<const float4*>(&X[bb][8]);
            const float4 x3 = *reinterpret_cast<const float4*>(&X[bb][12]);
            const float4 c4 = *reinterpret_cast<const float4*>(&C[bb][tg * 4]);
            const float idg = IDG[bb];
            const float ca[4] = {c4.x, c4.y, c4.z, c4.w};

            float y = 0.0f;
            #pragma unroll
            for (int jt = 0; jt < 4; ++jt) {
                float s = 0.0f;
                s = fmaf(Rf[jt][0].x, x0.x, s); s = fmaf(Rf[jt][0].y, x0.y, s);
                s = fmaf(Rf[jt][0].z, x0.z, s); s = fmaf(Rf[jt][0].w, x0.w, s);
                s = fmaf(Rf[jt][1].x, x1.x, s); s = fmaf(Rf[jt][1].y, x1.y, s);
                s = fmaf(Rf[jt][1].z, x1.z, s); s = fmaf(Rf[jt][1].w, x1.w, s);
                s = fmaf(Rf[jt][2].x, x2.x, s); s = fmaf(Rf[jt][2].y, x2.y, s);
                s = fmaf(Rf[jt][2].z, x2.z, s); s = fmaf(Rf[jt][2].w, x2.w, s);
                s = fmaf(Rf[jt][3].x, x3.x, s); s = fmaf(Rf[jt][3].y, x3.y, s);
                s = fmaf(Rf[jt][3].z, x3.z, s); s = fmaf(Rf[jt][3].w, x3.w, s);
                y = fmaf(ca[jt], s, y);
            }
            y += __shfl_xor(y, 16);
            y += __shfl_xor(y, 32);
            if (l < 16) part = fmaf(y * y, idg, part);
        }
    }

    #pragma unroll
    for (int off = 32; off > 0; off >>= 1)
        part += __shfl_down(part, off);
    __shared__ float wpart[4];
    if (l == 0) wpart[w] = part;
    __syncthreads();
    if (tid == 0) {
        const float v = wpart[0] + wpart[1] + wpart[2] + wpart[3];
        if (v != 0.0f) atomicAdd(out, v);
    }
}

extern "C" void kernel_launch(void* const* d_in, const int* in_sizes, int n_in,
                              void* d_out, int out_size, void* d_ws, size_t ws_size,
                              hipStream_t stream) {
    const float* reps  = (const float*)d_in[0];   // [16, N]
    const float* rmaps = (const float*)d_in[1];   // [16,16,16,16]
    const int*   ei    = (const int*)d_in[2];     // [2, E]
    const int*   types = (const int*)d_in[3];     // [N]
    float* out = (float*)d_out;

    const int E = in_sizes[2] / 2;
    const int N = in_sizes[3];

    char* ws = (char*)d_ws;
    const bool fast = (N == NNODES_C && E == E_C && ws_size >= FAST_NEED);

    if (fast) {
        unsigned short* entries = (unsigned short*)(ws + OFF_ENT);
        unsigned int*   cnt_g   = (unsigned int*)(ws + OFF_CNT);

        scatter_kernel  <<<NBLK,  256, 0, stream>>>(ei, types, entries, cnt_g, out, E);
        hist_node_kernel<<<NPART, 512, 0, stream>>>(reps, rmaps, entries, cnt_g,
                                                    types, out, N);
    } else {
        unsigned int* pk = (unsigned int*)ws;
        int* tcnt  = (int*)(ws + F_TCNT);
        int* tlist = (int*)(ws + F_TLIST);

        hipMemsetAsync(d_ws, 0, F_TLIST, stream);
        hipMemsetAsync(d_out, 0, sizeof(float), stream);
        edge_kernel<<<(E / 4 + 255) / 256, 256, 0, stream>>>(ei, types, pk, E);
        list_kernel<<<(N + 255) / 256, 256, 0, stream>>>(types, tcnt, tlist, N);
        dim3 grid(52, NT);
        node_kernel<<<grid, 256, 0, stream>>>(reps, rmaps, pk, tcnt, tlist, out, N);
    }
}